// Round 2
// baseline (244.073 us; speedup 1.0000x reference)
//
#include <hip/hip_runtime.h>

// B=2, T=2048, C=1024, H=16, D=64
// qkv row-major [4096, 3072]; y row-major [4096, 1024]; out fp32 [4096,1024]

typedef _Float16 h8 __attribute__((ext_vector_type(8)));
typedef _Float16 h4 __attribute__((ext_vector_type(4)));
typedef float f4 __attribute__((ext_vector_type(4)));

#define GLD_LDS16(g, l)                                                              \
  __builtin_amdgcn_global_load_lds((const __attribute__((address_space(1))) void*)(g), \
                                   (__attribute__((address_space(3))) void*)(l), 16, 0, 0)

// ---- cross-lane helpers (16-lane DPP rows == lane>>4 quads) ----
template <int CTRL>
__device__ __forceinline__ float dpp_shr_zero(float x) {  // shifted-in lanes read 0
  return __builtin_bit_cast(float,
      __builtin_amdgcn_update_dpp(0, __builtin_bit_cast(int, x), CTRL, 0xF, 0xF, true));
}
template <int CTRL>
__device__ __forceinline__ float dpp_shr_self(float x) {  // shifted-in lanes read own x
  int xi = __builtin_bit_cast(int, x);
  return __builtin_bit_cast(float,
      __builtin_amdgcn_update_dpp(xi, xi, CTRL, 0xF, 0xF, false));
}
__device__ __forceinline__ float scan16_add(float x) {  // inclusive prefix within 16-lane row
  x += dpp_shr_zero<0x111>(x);
  x += dpp_shr_zero<0x112>(x);
  x += dpp_shr_zero<0x114>(x);
  x += dpp_shr_zero<0x118>(x);
  return x;
}
__device__ __forceinline__ float scan16_max(float x) {  // inclusive max-scan
  x = fmaxf(x, dpp_shr_self<0x111>(x));
  x = fmaxf(x, dpp_shr_self<0x112>(x));
  x = fmaxf(x, dpp_shr_self<0x114>(x));
  x = fmaxf(x, dpp_shr_self<0x118>(x));
  return x;
}
__device__ __forceinline__ float bcast15(float x) {  // lane15 of each 16-lane group -> all
  return __builtin_bit_cast(float,
      __builtin_amdgcn_ds_swizzle(__builtin_bit_cast(int, x), 0x01F0));
}

__global__ __launch_bounds__(256) void f32_to_f16_kernel(const float* __restrict__ in,
                                                         _Float16* __restrict__ out, int n4) {
  int i = blockIdx.x * 256 + threadIdx.x;
  if (i < n4) {
    f4 v = *(const f4*)(in + (size_t)i * 4);
    h4 o;
    for (int j = 0; j < 4; ++j) o[j] = (_Float16)v[j];
    *(h4*)(out + (size_t)i * 4) = o;
  }
}

// C[M,N] = A[M,K] @ B[N,K]^T, fp16 in, fp32 accum. 128x128 tile, BK=32, 4 waves (2x2).
template <typename OutT>
__global__ __launch_bounds__(256) void gemm_nt_kernel(const _Float16* __restrict__ A,
                                                      const _Float16* __restrict__ B,
                                                      OutT* __restrict__ C,
                                                      int M, int N, int K) {
  __shared__ _Float16 As[128 * 32];
  __shared__ _Float16 Bs[128 * 32];
  const int tid = threadIdx.x;
  const int wave = tid >> 6, lane = tid & 63;
  const int wm = wave >> 1, wn = wave & 1;
  const int m0 = blockIdx.y * 128, n0 = blockIdx.x * 128;

  f4 acc[4][4] = {};

  for (int k0 = 0; k0 < K; k0 += 32) {
    __syncthreads();
    for (int r = 0; r < 2; ++r) {
      int cb = r * 256 + wave * 64;
      int chunk = cb + lane;
      int row = chunk >> 2;
      int col = (chunk & 3) * 8;
      GLD_LDS16(A + (size_t)(m0 + row) * K + k0 + col, As + cb * 8);
      GLD_LDS16(B + (size_t)(n0 + row) * K + k0 + col, Bs + cb * 8);
    }
    __syncthreads();
    h8 af[4], bf[4];
    const int kk = (lane >> 4) * 8;
    for (int mi = 0; mi < 4; ++mi)
      af[mi] = *(const h8*)(As + (wm * 64 + mi * 16 + (lane & 15)) * 32 + kk);
    for (int ni = 0; ni < 4; ++ni)
      bf[ni] = *(const h8*)(Bs + (wn * 64 + ni * 16 + (lane & 15)) * 32 + kk);
    for (int mi = 0; mi < 4; ++mi)
      for (int ni = 0; ni < 4; ++ni)
        acc[mi][ni] = __builtin_amdgcn_mfma_f32_16x16x32_f16(af[mi], bf[ni], acc[mi][ni], 0, 0, 0);
  }
  for (int mi = 0; mi < 4; ++mi)
    for (int ni = 0; ni < 4; ++ni)
      for (int i = 0; i < 4; ++i) {
        int m = m0 + wm * 64 + mi * 16 + (lane >> 4) * 4 + i;
        int n = n0 + wn * 64 + ni * 16 + (lane & 15);
        C[(size_t)m * N + n] = (OutT)acc[mi][ni][i];
      }
}

// Fused penalized attention, register-resident softmax state + DPP scans.
// Grid = 512: bh (32) x pair (16); block does q-tiles {pair, 31-pair} = 33 k-iters.
__global__ __launch_bounds__(256, 2) void attn_kernel(const _Float16* __restrict__ qkv,
                                                      _Float16* __restrict__ yh) {
  __shared__ _Float16 Qs[64 * 72];      // [qrow][d], pre-scaled by 1/8
  __shared__ _Float16 Ks[2][64 * 72];   // [krow][d], double-buffered
  __shared__ _Float16 Vt[2][64 * 72];   // [d][krow], double-buffered
  __shared__ _Float16 Ws[64 * 72];      // weights [qrow][krow] (wave-private rows)

  const int tid = threadIdx.x;
  const int wave = tid >> 6, lane = tid & 63;
  const int l16 = lane & 15, q = lane >> 4;
  const int bh = blockIdx.x >> 4, pair = blockIdx.x & 15;
  const int b = bh >> 4, h = bh & 15;
  const size_t base = (size_t)b * 2048 * 3072 + h * 64;

  for (int qsel = 0; qsel < 2; ++qsel) {
    const int qt = qsel ? (31 - pair) : pair;
    __syncthreads();  // prior q-tile's reads of Qs complete
    for (int j = 0; j < 2; ++j) {
      int chunk = tid + 256 * j;
      int row = chunk >> 3, c8 = chunk & 7;
      h8 qv = *(const h8*)(qkv + base + (size_t)(qt * 64 + row) * 3072 + c8 * 8);
      for (int e = 0; e < 8; ++e) qv[e] = qv[e] * (_Float16)0.125f;
      *(h8*)(Qs + row * 72 + c8 * 8) = qv;
    }
    f4 Oacc[4] = {};
    float m_r[4], l_r[4], c_r[4];
#pragma unroll
    for (int i = 0; i < 4; ++i) { m_r[i] = -1e30f; l_r[i] = 0.f; c_r[i] = 0.f; }

    for (int kt = 0; kt <= qt; ++kt) {
      _Float16* ksb = Ks[kt & 1];
      _Float16* vtb = Vt[kt & 1];
      // stage K tile (row-major)
      for (int j = 0; j < 2; ++j) {
        int chunk = tid + 256 * j;
        int row = chunk >> 3, c8 = chunk & 7;
        h8 kv = *(const h8*)(qkv + base + (size_t)(kt * 64 + row) * 3072 + 1024 + c8 * 8);
        *(h8*)(ksb + row * 72 + c8 * 8) = kv;
      }
      // stage V transposed (lane = d, coalesced 128B per t-row)
      {
        const _Float16* vg = qkv + base + 2048 + lane;
        h8 v0, v1;
        for (int j = 0; j < 8; ++j) v0[j] = vg[(size_t)(kt * 64 + wave * 16 + j) * 3072];
        for (int j = 0; j < 8; ++j) v1[j] = vg[(size_t)(kt * 64 + wave * 16 + 8 + j) * 3072];
        *(h8*)(vtb + lane * 72 + wave * 16) = v0;
        *(h8*)(vtb + lane * 72 + wave * 16 + 8) = v1;
      }
      __syncthreads();  // the ONLY barrier per k-tile (dbuf covers kt+2 overwrite)

      // P = Qs @ Ks^T; wave owns q-rows [16w,16w+16): row=4q+i, col(key)=16ni+l16
      f4 pacc[4] = {};
#pragma unroll
      for (int ks = 0; ks < 2; ++ks) {
        h8 af = *(const h8*)(Qs + (16 * wave + l16) * 72 + ks * 32 + q * 8);
#pragma unroll
        for (int ni = 0; ni < 4; ++ni) {
          h8 bf = *(const h8*)(ksb + (16 * ni + l16) * 72 + ks * 32 + q * 8);
          pacc[ni] = __builtin_amdgcn_mfma_f32_16x16x32_f16(af, bf, pacc[ni], 0, 0, 0);
        }
      }
      const bool diag = (kt == qt);
      const int rl = 16 * wave + 4 * q;
      float Lv[4][4], rmax[4];
#pragma unroll
      for (int i = 0; i < 4; ++i) rmax[i] = -1e30f;
#pragma unroll
      for (int ni = 0; ni < 4; ++ni) {
        const int col = 16 * ni + l16;
#pragma unroll
        for (int i = 0; i < 4; ++i) {
          float p = pacc[ni][i];
          bool val = (!diag) || (col <= rl + i);
          float s = val ? __builtin_amdgcn_rcpf(1.f + __expf(-p)) : 0.f;
          float incl = scan16_add(s);                       // prefix of sigma along cols
          float L = val ? (p + c_r[i] + (incl - s)) : -1e30f;
          Lv[ni][i] = L;
          rmax[i] = fmaxf(rmax[i], L);
          c_r[i] += bcast15(incl);                          // += block total
        }
      }
      float mn[4], al[4];
#pragma unroll
      for (int i = 0; i < 4; ++i) {
        float gm = bcast15(scan16_max(rmax[i]));
        mn[i] = fmaxf(m_r[i], gm);
        al[i] = __expf(m_r[i] - mn[i]);
        m_r[i] = mn[i];
      }
      float wacc[4] = {0.f, 0.f, 0.f, 0.f};
#pragma unroll
      for (int ni = 0; ni < 4; ++ni)
#pragma unroll
        for (int i = 0; i < 4; ++i) {
          float w = __expf(Lv[ni][i] - mn[i]);
          Ws[(16 * wave + 4 * q + i) * 72 + 16 * ni + l16] = (_Float16)w;  // C->A transpose
          wacc[i] += w;
        }
#pragma unroll
      for (int i = 0; i < 4; ++i)
        l_r[i] = l_r[i] * al[i] + bcast15(scan16_add(wacc[i]));
#pragma unroll
      for (int ni = 0; ni < 4; ++ni)
#pragma unroll
        for (int i = 0; i < 4; ++i) Oacc[ni][i] *= al[i];
      // O += Ws @ V   (Ws rows wave-private: no barrier, compiler waits lgkmcnt)
#pragma unroll
      for (int ks = 0; ks < 2; ++ks) {
        h8 af = *(const h8*)(Ws + (16 * wave + l16) * 72 + ks * 32 + q * 8);
#pragma unroll
        for (int ni = 0; ni < 4; ++ni) {
          h8 bf = *(const h8*)(vtb + (16 * ni + l16) * 72 + ks * 32 + q * 8);
          Oacc[ni] = __builtin_amdgcn_mfma_f32_16x16x32_f16(af, bf, Oacc[ni], 0, 0, 0);
        }
      }
    }  // kt
#pragma unroll
    for (int ni = 0; ni < 4; ++ni)
#pragma unroll
      for (int i = 0; i < 4; ++i) {
        int t = qt * 64 + 16 * wave + 4 * q + i;
        float yv = Oacc[ni][i] * __builtin_amdgcn_rcpf(l_r[i]);
        yh[((size_t)(b * 2048 + t)) * 1024 + h * 64 + 16 * ni + l16] = (_Float16)yv;
      }
  }  // qsel
}

extern "C" void kernel_launch(void* const* d_in, const int* in_sizes, int n_in,
                              void* d_out, int out_size, void* d_ws, size_t ws_size,
                              hipStream_t stream) {
  const float* x  = (const float*)d_in[0];   // [2,2048,1024]
  const float* Wa = (const float*)d_in[1];   // [3072,1024]
  const float* Wp = (const float*)d_in[2];   // [1024,1024]
  float* out = (float*)d_out;                // [4096,1024] fp32

  char* ws = (char*)d_ws;
  _Float16* xh   = (_Float16*)(ws);                    //  8 MB
  _Float16* wah  = (_Float16*)(ws + 8388608);          //  6 MB
  _Float16* wph  = (_Float16*)(ws + 14680064);         //  2 MB
  _Float16* qkvh = (_Float16*)(ws + 16777216);         // 24 MB
  _Float16* yh   = (_Float16*)(ws + 41943040);         //  8 MB

  f32_to_f16_kernel<<<4096, 256, 0, stream>>>(x,  xh,  4194304 / 4);
  f32_to_f16_kernel<<<3072, 256, 0, stream>>>(Wa, wah, 3145728 / 4);
  f32_to_f16_kernel<<<1024, 256, 0, stream>>>(Wp, wph, 1048576 / 4);

  gemm_nt_kernel<_Float16><<<dim3(24, 32), 256, 0, stream>>>(xh, wah, qkvh, 4096, 3072, 1024);
  attn_kernel<<<512, 256, 0, stream>>>(qkvh, yh);
  gemm_nt_kernel<float><<<dim3(8, 32), 256, 0, stream>>>(yh, wph, out, 4096, 1024, 1024);
}

// Round 3
// 231.578 us; speedup vs baseline: 1.0540x; 1.0540x over previous
//
#include <hip/hip_runtime.h>

// B=2, T=2048, C=1024, H=16, D=64
// qkv row-major [4096, 3072]; y row-major [4096, 1024]; out fp32 [4096,1024]

typedef _Float16 h8 __attribute__((ext_vector_type(8)));
typedef _Float16 h4 __attribute__((ext_vector_type(4)));
typedef float f4 __attribute__((ext_vector_type(4)));

#define GLD_LDS16(g, l)                                                              \
  __builtin_amdgcn_global_load_lds((const __attribute__((address_space(1))) void*)(g), \
                                   (__attribute__((address_space(3))) void*)(l), 16, 0, 0)

// ---- cross-lane helpers (16-lane DPP rows) ----
template <int CTRL>
__device__ __forceinline__ float dpp_shr_zero(float x) {  // shifted-in lanes read 0
  return __builtin_bit_cast(float,
      __builtin_amdgcn_update_dpp(0, __builtin_bit_cast(int, x), CTRL, 0xF, 0xF, true));
}
template <int CTRL>
__device__ __forceinline__ float dpp_shr_self(float x) {  // shifted-in lanes read own x
  int xi = __builtin_bit_cast(int, x);
  return __builtin_bit_cast(float,
      __builtin_amdgcn_update_dpp(xi, xi, CTRL, 0xF, 0xF, false));
}
__device__ __forceinline__ float scan16_add(float x) {  // inclusive prefix within 16-lane row
  x += dpp_shr_zero<0x111>(x);
  x += dpp_shr_zero<0x112>(x);
  x += dpp_shr_zero<0x114>(x);
  x += dpp_shr_zero<0x118>(x);
  return x;
}
__device__ __forceinline__ float scan16_max(float x) {  // inclusive max-scan
  x = fmaxf(x, dpp_shr_self<0x111>(x));
  x = fmaxf(x, dpp_shr_self<0x112>(x));
  x = fmaxf(x, dpp_shr_self<0x114>(x));
  x = fmaxf(x, dpp_shr_self<0x118>(x));
  return x;
}
__device__ __forceinline__ float bcast15(float x) {  // lane15 of each 16-lane group -> group
  return __builtin_bit_cast(float,
      __builtin_amdgcn_ds_swizzle(__builtin_bit_cast(int, x), 0x01F0));
}

__global__ __launch_bounds__(256) void f32_to_f16_kernel(const float* __restrict__ in,
                                                         _Float16* __restrict__ out, int n4) {
  int i = blockIdx.x * 256 + threadIdx.x;
  if (i < n4) {
    f4 v = *(const f4*)(in + (size_t)i * 4);
    h4 o;
    for (int j = 0; j < 4; ++j) o[j] = (_Float16)v[j];
    *(h4*)(out + (size_t)i * 4) = o;
  }
}

// C[M,N] = A[M,K] @ B[N,K]^T, fp16 in, fp32 accum. 128x128 tile, BK=32, 4 waves (2x2).
template <typename OutT>
__global__ __launch_bounds__(256) void gemm_nt_kernel(const _Float16* __restrict__ A,
                                                      const _Float16* __restrict__ B,
                                                      OutT* __restrict__ C,
                                                      int M, int N, int K) {
  __shared__ _Float16 As[128 * 32];
  __shared__ _Float16 Bs[128 * 32];
  const int tid = threadIdx.x;
  const int wave = tid >> 6, lane = tid & 63;
  const int wm = wave >> 1, wn = wave & 1;
  const int m0 = blockIdx.y * 128, n0 = blockIdx.x * 128;

  f4 acc[4][4] = {};

  for (int k0 = 0; k0 < K; k0 += 32) {
    __syncthreads();
    for (int r = 0; r < 2; ++r) {
      int cb = r * 256 + wave * 64;
      int chunk = cb + lane;
      int row = chunk >> 2;
      int col = (chunk & 3) * 8;
      GLD_LDS16(A + (size_t)(m0 + row) * K + k0 + col, As + cb * 8);
      GLD_LDS16(B + (size_t)(n0 + row) * K + k0 + col, Bs + cb * 8);
    }
    __syncthreads();
    h8 af[4], bf[4];
    const int kk = (lane >> 4) * 8;
    for (int mi = 0; mi < 4; ++mi)
      af[mi] = *(const h8*)(As + (wm * 64 + mi * 16 + (lane & 15)) * 32 + kk);
    for (int ni = 0; ni < 4; ++ni)
      bf[ni] = *(const h8*)(Bs + (wn * 64 + ni * 16 + (lane & 15)) * 32 + kk);
    for (int mi = 0; mi < 4; ++mi)
      for (int ni = 0; ni < 4; ++ni)
        acc[mi][ni] = __builtin_amdgcn_mfma_f32_16x16x32_f16(af[mi], bf[ni], acc[mi][ni], 0, 0, 0);
  }
  for (int mi = 0; mi < 4; ++mi)
    for (int ni = 0; ni < 4; ++ni)
      for (int i = 0; i < 4; ++i) {
        int m = m0 + wm * 64 + mi * 16 + (lane >> 4) * 4 + i;
        int n = n0 + wn * 64 + ni * 16 + (lane & 15);
        C[(size_t)m * N + n] = (OutT)acc[mi][ni][i];
      }
}

// Fused penalized attention. Grid = 1024: (31-qt) in high 5 bits (longest blocks launch
// first), bh in low 5. One q-tile per block; 36 KB LDS -> 4 blocks/CU (16 waves).
// Next K/V tile is prefetched into registers (single-buffer LDS, 2 barriers/iter).
__global__ __launch_bounds__(256, 4) void attn_kernel(const _Float16* __restrict__ qkv,
                                                      _Float16* __restrict__ yh) {
  __shared__ _Float16 Qs[64 * 72];   // [qrow][d], pre-scaled by 1/8
  __shared__ _Float16 Ks[64 * 72];   // [krow][d]
  __shared__ _Float16 Vt[64 * 72];   // [d][krow]
  __shared__ _Float16 Ws[64 * 72];   // weights [qrow][krow] (wave-private rows)

  const int tid = threadIdx.x;
  const int wave = tid >> 6, lane = tid & 63;
  const int l16 = lane & 15, q = lane >> 4;
  const int qt = 31 - (blockIdx.x >> 5);
  const int bh = blockIdx.x & 31;
  const int b = bh >> 4, h = bh & 15;
  const size_t base = (size_t)b * 2048 * 3072 + h * 64;

  // Q tile load (scaled by 1/sqrt(D) = 0.125, exact in fp16)
  const int srow0 = tid >> 3, sc8 = tid & 7;          // chunk 0: rows 0..31
  const int srow1 = srow0 + 32;                       // chunk 1: rows 32..63
  {
    h8 q0 = *(const h8*)(qkv + base + (size_t)(qt * 64 + srow0) * 3072 + sc8 * 8);
    h8 q1 = *(const h8*)(qkv + base + (size_t)(qt * 64 + srow1) * 3072 + sc8 * 8);
    for (int e = 0; e < 8; ++e) { q0[e] = q0[e] * (_Float16)0.125f; q1[e] = q1[e] * (_Float16)0.125f; }
    *(h8*)(Qs + srow0 * 72 + sc8 * 8) = q0;
    *(h8*)(Qs + srow1 * 72 + sc8 * 8) = q1;
  }

  // prefetch kt=0 K/V into registers
  h8 kr0, kr1, vr0, vr1;
  {
    const _Float16* kg = qkv + base + 1024;
    kr0 = *(const h8*)(kg + (size_t)srow0 * 3072 + sc8 * 8);
    kr1 = *(const h8*)(kg + (size_t)srow1 * 3072 + sc8 * 8);
    const _Float16* vg = qkv + base + 2048 + lane;
    for (int j = 0; j < 8; ++j) vr0[j] = vg[(size_t)(wave * 16 + j) * 3072];
    for (int j = 0; j < 8; ++j) vr1[j] = vg[(size_t)(wave * 16 + 8 + j) * 3072];
  }

  f4 Oacc[4] = {};
  float m_r[4], l_r[4], c_r[4];
#pragma unroll
  for (int i = 0; i < 4; ++i) { m_r[i] = -1e30f; l_r[i] = 0.f; c_r[i] = 0.f; }

  for (int kt = 0; kt <= qt; ++kt) {
    __syncthreads();  // B1: prior iteration's LDS reads (and Q-writes on iter 0) done
    *(h8*)(Ks + srow0 * 72 + sc8 * 8) = kr0;
    *(h8*)(Ks + srow1 * 72 + sc8 * 8) = kr1;
    *(h8*)(Vt + lane * 72 + wave * 16) = vr0;
    *(h8*)(Vt + lane * 72 + wave * 16 + 8) = vr1;
    __syncthreads();  // B2: staging visible

    // prefetch kt+1 (consumed at next B1; latency hidden under compute below)
    if (kt < qt) {
      const _Float16* kg = qkv + base + (size_t)(kt + 1) * 64 * 3072 + 1024;
      kr0 = *(const h8*)(kg + (size_t)srow0 * 3072 + sc8 * 8);
      kr1 = *(const h8*)(kg + (size_t)srow1 * 3072 + sc8 * 8);
      const _Float16* vg = qkv + base + (size_t)(kt + 1) * 64 * 3072 + 2048 + lane;
      for (int j = 0; j < 8; ++j) vr0[j] = vg[(size_t)(wave * 16 + j) * 3072];
      for (int j = 0; j < 8; ++j) vr1[j] = vg[(size_t)(wave * 16 + 8 + j) * 3072];
    }

    // P = Qs @ Ks^T; wave owns q-rows [16w,16w+16): row = 4q+i, col(key) = 16ni+l16
    f4 pacc[4] = {};
#pragma unroll
    for (int ks = 0; ks < 2; ++ks) {
      h8 af = *(const h8*)(Qs + (16 * wave + l16) * 72 + ks * 32 + q * 8);
#pragma unroll
      for (int ni = 0; ni < 4; ++ni) {
        h8 bf = *(const h8*)(Ks + (16 * ni + l16) * 72 + ks * 32 + q * 8);
        pacc[ni] = __builtin_amdgcn_mfma_f32_16x16x32_f16(af, bf, pacc[ni], 0, 0, 0);
      }
    }

    const bool diag = (kt == qt);
    const int rl = 16 * wave + 4 * q;
    // Pass 1 (independent per element): sigma, 16-lane scan, block totals.
    // pacc <- p + (exclusive in-block prefix); tot = block sum (broadcast)
    float tot[4][4];
#pragma unroll
    for (int ni = 0; ni < 4; ++ni) {
      const int col = 16 * ni + l16;
#pragma unroll
      for (int i = 0; i < 4; ++i) {
        float p = pacc[ni][i];
        bool val = (!diag) || (col <= rl + i);
        float s = val ? __builtin_amdgcn_rcpf(1.f + __expf(-p)) : 0.f;
        float incl = scan16_add(s);
        tot[ni][i] = bcast15(incl);
        pacc[ni][i] = val ? (p + (incl - s)) : -1e30f;
      }
    }
    // Pass 2: fold cross-block offsets (cheap serial adds), row max
    float rmax[4];
#pragma unroll
    for (int i = 0; i < 4; ++i) {
      float o = c_r[i], mx = -1e30f;
#pragma unroll
      for (int ni = 0; ni < 4; ++ni) {
        float L = pacc[ni][i] + o;   // masked: -1e30 + o stays ~-1e30
        pacc[ni][i] = L;
        mx = fmaxf(mx, L);
        o += tot[ni][i];
      }
      c_r[i] = o;
      rmax[i] = mx;
    }
    float mn[4], al[4];
#pragma unroll
    for (int i = 0; i < 4; ++i) {
      float gm = bcast15(scan16_max(rmax[i]));
      mn[i] = fmaxf(m_r[i], gm);
      al[i] = __expf(m_r[i] - mn[i]);
      m_r[i] = mn[i];
    }
    float wacc[4] = {0.f, 0.f, 0.f, 0.f};
#pragma unroll
    for (int ni = 0; ni < 4; ++ni)
#pragma unroll
      for (int i = 0; i < 4; ++i) {
        float w = __expf(pacc[ni][i] - mn[i]);
        Ws[(16 * wave + 4 * q + i) * 72 + 16 * ni + l16] = (_Float16)w;  // C->A transpose
        wacc[i] += w;
      }
#pragma unroll
    for (int i = 0; i < 4; ++i)
      l_r[i] = l_r[i] * al[i] + bcast15(scan16_add(wacc[i]));
#pragma unroll
    for (int ni = 0; ni < 4; ++ni)
#pragma unroll
      for (int i = 0; i < 4; ++i) Oacc[ni][i] *= al[i];
    // O += Ws @ V   (Ws rows wave-private; compiler inserts lgkmcnt wait)
#pragma unroll
    for (int ks = 0; ks < 2; ++ks) {
      h8 af = *(const h8*)(Ws + (16 * wave + l16) * 72 + ks * 32 + q * 8);
#pragma unroll
      for (int ni = 0; ni < 4; ++ni) {
        h8 bf = *(const h8*)(Vt + (16 * ni + l16) * 72 + ks * 32 + q * 8);
        Oacc[ni] = __builtin_amdgcn_mfma_f32_16x16x32_f16(af, bf, Oacc[ni], 0, 0, 0);
      }
    }
  }  // kt

#pragma unroll
  for (int ni = 0; ni < 4; ++ni)
#pragma unroll
    for (int i = 0; i < 4; ++i) {
      int t = qt * 64 + 16 * wave + 4 * q + i;
      float yv = Oacc[ni][i] * __builtin_amdgcn_rcpf(l_r[i]);
      yh[((size_t)(b * 2048 + t)) * 1024 + h * 64 + 16 * ni + l16] = (_Float16)yv;
    }
}

extern "C" void kernel_launch(void* const* d_in, const int* in_sizes, int n_in,
                              void* d_out, int out_size, void* d_ws, size_t ws_size,
                              hipStream_t stream) {
  const float* x  = (const float*)d_in[0];   // [2,2048,1024]
  const float* Wa = (const float*)d_in[1];   // [3072,1024]
  const float* Wp = (const float*)d_in[2];   // [1024,1024]
  float* out = (float*)d_out;                // [4096,1024] fp32

  char* ws = (char*)d_ws;
  _Float16* xh   = (_Float16*)(ws);                    //  8 MB
  _Float16* wah  = (_Float16*)(ws + 8388608);          //  6 MB
  _Float16* wph  = (_Float16*)(ws + 14680064);         //  2 MB
  _Float16* qkvh = (_Float16*)(ws + 16777216);         // 24 MB
  _Float16* yh   = (_Float16*)(ws + 41943040);         //  8 MB

  f32_to_f16_kernel<<<4096, 256, 0, stream>>>(x,  xh,  4194304 / 4);
  f32_to_f16_kernel<<<3072, 256, 0, stream>>>(Wa, wah, 3145728 / 4);
  f32_to_f16_kernel<<<1024, 256, 0, stream>>>(Wp, wph, 1048576 / 4);

  gemm_nt_kernel<_Float16><<<dim3(24, 32), 256, 0, stream>>>(xh, wah, qkvh, 4096, 3072, 1024);
  attn_kernel<<<1024, 256, 0, stream>>>(qkvh, yh);
  gemm_nt_kernel<float><<<dim3(8, 32), 256, 0, stream>>>(yh, wph, out, 4096, 1024, 1024);
}